// Round 5
// baseline (787.937 us; speedup 1.0000x reference)
//
#include <hip/hip_runtime.h>
#include <math.h>

#define BB 512
#define NN 16
#define CC 256
#define KK 8192
#define BNC (BB*NN*CC)

typedef unsigned short u16;
typedef __attribute__((ext_vector_type(8))) short bf16x8;
typedef __attribute__((ext_vector_type(4))) float f32x4;

__device__ __forceinline__ u16 f2bf(float x) {
    unsigned u = __float_as_uint(x);
    unsigned r = (u + 0x7fffu + ((u >> 16) & 1u)) >> 16;
    return (u16)r;
}

__device__ __forceinline__ void gl2lds16(const void* g, void* l) {
    __builtin_amdgcn_global_load_lds(
        (const __attribute__((address_space(1))) void*)g,
        (__attribute__((address_space(3))) void*)l,
        16, 0, 0);
}

__device__ __forceinline__ void gl2lds4(const void* g, void* l) {
    __builtin_amdgcn_global_load_lds(
        (const __attribute__((address_space(1))) void*)g,
        (__attribute__((address_space(3))) void*)l,
        4, 0, 0);
}

// ---------------------------------------------------------------------------
// stores 0.5*|e|^2 (folded into MFMA acc init in dist kernel)
__global__ void esq_kernel(const float* __restrict__ emb, float* __restrict__ e_sq) {
    int gid  = blockIdx.x * blockDim.x + threadIdx.x;
    int wave = gid >> 6;
    int lane = gid & 63;
    const float4 v = *(const float4*)(emb + (size_t)wave * CC + lane * 4);
    float s = v.x*v.x + v.y*v.y + v.z*v.z + v.w*v.w;
    #pragma unroll
    for (int m = 32; m >= 1; m >>= 1) s += __shfl_xor(s, m, 64);
    if (lane == 0) e_sq[wave] = 0.5f * s;
}

// stores NEGATED emb in bf16 so MFMA accumulates 0.5*esq - dot
__global__ void cvt_emb_kernel(const float* __restrict__ emb, u16* __restrict__ out) {
    int gid = blockIdx.x * blockDim.x + threadIdx.x;
    float4 v = ((const float4*)emb)[gid];
    ushort4 o;
    o.x = f2bf(-v.x); o.y = f2bf(-v.y); o.z = f2bf(-v.z); o.w = f2bf(-v.w);
    ((ushort4*)out)[gid] = o;
}

// initial pool for pn=1
__global__ void init_pool_kernel(const float* __restrict__ f,
                                 u16* __restrict__ rest_bf) {
    int b = blockIdx.x;
    int c = threadIdx.x;
    const float* base = f + (size_t)b * NN * CC + c;
    float acc = 0.f;
    #pragma unroll
    for (int n = 0; n < NN; ++n) acc += base[(size_t)n * CC];
    rest_bf[(size_t)b * CC + c] = f2bf(acc * (1.0f / 16.0f));
}

// ---------------------------------------------------------------------------
__device__ __forceinline__ unsigned long long shfl_xor_u64(unsigned long long v, int m) {
    unsigned lo = (unsigned)v, hi = (unsigned)(v >> 32);
    lo = __shfl_xor(lo, m, 64);
    hi = __shfl_xor(hi, m, 64);
    return ((unsigned long long)hi << 32) | lo;
}

// MFMA distance+argmin, v6 (shared code stream, 8-phase style):
//  - Block = 256 rows: wave w owns rows r0+w*64.., resident in regs bf[4][8]
//    (loaded once; zero in-loop traffic for rows).
//  - Codes staged into a BLOCK-SHARED 4-deep LDS ring (chunk = 64 codes x
//    64B K-slice = 4KB; 1 gl2lds16 per thread per phase) -> code L2 traffic
//    drops 4x vs wave-private staging.
//  - Granule XOR-swizzle slot(c,g)=4c+(g^((c>>1)&3)), applied by
//    pre-swizzling the per-lane GLOBAL source (linear LDS dest, rule: both
//    sides or neither). Each 16-lane quarter covers every bank residue
//    exactly 2x -> conflict-free ds_read_b128 (2-way is free).
//  - Per phase: s_waitcnt vmcnt(2) (counted, never 0) + s_barrier;
//    explicit lgkmcnt(0) before the barrier so no wave's ds_read is in
//    flight when the t+3 stage overwrites that buffer.
//  - esq strip (<=512 floats) staged entirely in the prologue -> uniform
//    in-loop vmcnt literals; eqv reads are broadcast (conflict-free).
//  - LDS 66KB caps occupancy at 2 blocks/CU -> register budget 256
//    (prevents the v2/v3 spill-for-occupancy failure; proven in v5).
__global__ __launch_bounds__(256, 2) void dist_mfma_kernel(
        const u16* __restrict__ A, const u16* __restrict__ Bm,
        const float* __restrict__ e_sq,
        unsigned long long* __restrict__ packed, int cpb) {
    __shared__ __align__(16) u16 sC[32768];   // 64KB: first 16KB = 4-chunk ring; rest = occupancy pad
    __shared__ __align__(16) float sE[512];   // whole esq strip for this block
    const int tid = threadIdx.x;
    const int w = tid >> 6, l = tid & 63;
    const int r0 = blockIdx.x * 256;
    const int c0 = blockIdx.y * cpb;
    const int nch = cpb >> 3;    // chunks = (cpb/64)*8
    const int ncb2 = cpb >> 6;   // 64-code blocks
    const int arow = l & 15;
    const int aq   = l >> 4;

    // ---- resident row fragments: wave w owns rows r0+w*64+j*16+arow ----
    bf16x8 bf[4][8];
    {
        const u16* fb = A + (((size_t)(r0 + w * 64 + arow)) << 8) + aq * 8;
        #pragma unroll
        for (int j = 0; j < 4; ++j)
            #pragma unroll
            for (int kc = 0; kc < 8; ++kc)
                bf[j][kc] = *(const bf16x8*)(fb + (j << 12) + (kc << 5));
    }

    // ---- esq strip staged whole in prologue (cpb <= 512) ----
    for (int n = tid; n < cpb; n += 256)
        gl2lds4(e_sq + c0 + n, (char*)sE + (size_t)(n - l) * 4);

    // ---- code chunk staging: thread covers slot s = w*64 + l of the 4KB
    // chunk: code crel = s>>2, stored granule index s&3 must receive actual
    // granule g = (s&3) ^ ((s>>3)&3)  (pre-swizzled source, linear dest).
    const int crel = w * 16 + (l >> 2);
    const int g = (l & 3) ^ ((l >> 3) & 3);
    const u16* Pb = Bm + (((size_t)(c0 + crel)) << 8) + g * 8;

    #define STAGEC(t_) { \
        int tt_ = (t_); if (tt_ >= nch) tt_ = nch - 1; \
        const u16* s_ = Pb + (((size_t)(tt_ >> 3)) << 14) + ((tt_ & 7) << 5); \
        gl2lds16(s_, (char*)sC + (((t_) & 3) << 12) + (w << 10)); }

    STAGEC(0) STAGEC(1) STAGEC(2)

    const int gx = aq ^ ((arow >> 1) & 3);   // read-side granule swizzle
    float bestd[4];
    int   bestk[4];
    #pragma unroll
    for (int j = 0; j < 4; ++j) { bestd[j] = 1e30f; bestk[j] = 0; }

    for (int cb = 0; cb < ncb2; ++cb) {
        f32x4 acc[4][4];
        #pragma unroll
        for (int kc = 0; kc < 8; ++kc) {
            const int t = cb * 8 + kc;
            // chunk t landed (own wave's quarter): leave t+1,t+2 in flight
            asm volatile("s_waitcnt vmcnt(2)" ::: "memory");
            // all waves' quarters landed; all reads of chunk t-1 retired
            __builtin_amdgcn_s_barrier();
            STAGEC(t + 3)           // overwrites buf (t-1)&3: safe per above
            if (kc == 0) {
                #pragma unroll
                for (int i = 0; i < 4; ++i) {
                    f32x4 ev = *(const f32x4*)(sE + cb * 64 + i * 16 + (aq << 2));
                    #pragma unroll
                    for (int j = 0; j < 4; ++j) acc[i][j] = ev;
                }
            }
            bf16x8 cf[4];
            const u16* cbp = sC + ((t & 3) << 11);
            #pragma unroll
            for (int i = 0; i < 4; ++i)
                cf[i] = *(const bf16x8*)(cbp + ((i * 16 + arow) << 5) + (gx << 3));
            __builtin_amdgcn_s_setprio(1);
            #pragma unroll
            for (int i = 0; i < 4; ++i)
                #pragma unroll
                for (int j = 0; j < 4; ++j)
                    acc[i][j] = __builtin_amdgcn_mfma_f32_16x16x32_bf16(
                                    cf[i], bf[j][kc], acc[i][j], 0, 0, 0);
            __builtin_amdgcn_s_setprio(0);
            // retire this phase's ds_reads before the next barrier
            asm volatile("s_waitcnt lgkmcnt(0)" ::: "memory");
        }

        // fold: acc holds 0.5*d; argmin per f-row (j) over this cb's 16 codes/lane
        #pragma unroll
        for (int i = 0; i < 4; ++i)
            #pragma unroll
            for (int r = 0; r < 4; ++r) {
                const int k = c0 + cb * 64 + i * 16 + (aq << 2) + r;
                #pragma unroll
                for (int j = 0; j < 4; ++j) {
                    const float d = acc[i][j][r];
                    if (d < bestd[j]) { bestd[j] = d; bestk[j] = k; }
                }
            }
    }
    #undef STAGEC

    // merge across the 4 aq-lanes holding the same f-row, then global merge
    #pragma unroll
    for (int j = 0; j < 4; ++j) {
        unsigned u = __float_as_uint(bestd[j]);
        u = (u & 0x80000000u) ? ~u : (u | 0x80000000u);
        unsigned long long p = ((unsigned long long)u << 32) | (unsigned)bestk[j];
        unsigned long long o = shfl_xor_u64(p, 16);
        if (o < p) p = o;
        o = shfl_xor_u64(p, 32);
        if (o < p) p = o;
        if (aq == 0)
            atomicMin(&packed[r0 + w * 64 + j * 16 + arow], p);
    }
}

// ---------------------------------------------------------------------------
// Fused: gather + upsample + f_hat/f_rest update + qlat partial + pool for pn+1.
__global__ void update_pool_kernel(const float* __restrict__ f,
                                   const float* __restrict__ emb,
                                   const unsigned long long* __restrict__ packed,
                                   float* __restrict__ f_rest,
                                   float* __restrict__ f_hat,
                                   float* __restrict__ slots,
                                   u16* __restrict__ rest_bf, int pn) {
    int b = blockIdx.x;
    int c = threadIdx.x;
    __shared__ int sk[NN];
    __shared__ float red[4];
    if (threadIdx.x < pn)
        sk[threadIdx.x] = (int)(unsigned)(packed[b * pn + threadIdx.x] & 0xffffffffull);
    __syncthreads();

    float fr[NN];
    float acc_sq = 0.f;
    #pragma unroll
    for (int n = 0; n < NN; ++n) {
        double pos = (n + 0.5) * ((double)pn / 16.0) - 0.5;
        if (pos < 0.0) pos = 0.0;
        int i0 = (int)floor(pos);
        if (i0 > pn - 1) i0 = pn - 1;
        int i1 = i0 + 1;
        if (i1 > pn - 1) i1 = pn - 1;
        double frac = pos - (double)i0;
        float w1 = (float)frac;
        float w0 = (float)(1.0 - frac);
        float h = w0 * emb[(size_t)sk[i0] * CC + c] + w1 * emb[(size_t)sk[i1] * CC + c];
        size_t off = ((size_t)b * NN + n) * CC + c;
        float fh = f_hat[off] + h;
        f_hat[off] = fh;
        float fre = f_rest[off] - h;
        f_rest[off] = fre;
        fr[n] = fre;
        float diff = fh - f[off];
        acc_sq += diff * diff;
    }

    int wv = threadIdx.x >> 6, ln = threadIdx.x & 63;
    #pragma unroll
    for (int m = 32; m >= 1; m >>= 1) acc_sq += __shfl_xor(acc_sq, m, 64);
    if (ln == 0) red[wv] = acc_sq;

    int pn2 = pn + 1;
    if (pn < NN) {
        for (int p = 0; p < pn2; ++p) {
            int s = (p * NN) / pn2;
            int e = ((p + 1) * NN + pn2 - 1) / pn2;
            float v = 0.f;
            for (int n = s; n < e; ++n) v += fr[n];
            v *= 1.0f / (float)(e - s);
            rest_bf[((size_t)(b * pn2 + p)) * CC + c] = f2bf(v);
        }
    }
    __syncthreads();
    if (threadIdx.x == 0)
        atomicAdd(&slots[b & 255], (red[0] + red[1]) + (red[2] + red[3]));
}

// ---------------------------------------------------------------------------
__global__ void final_kernel(const float* __restrict__ slots, float* __restrict__ out_scalars) {
    float v = slots[threadIdx.x];
    #pragma unroll
    for (int m = 32; m >= 1; m >>= 1) v += __shfl_xor(v, m, 64);
    __shared__ float red[4];
    int wv = threadIdx.x >> 6, ln = threadIdx.x & 63;
    if (ln == 0) red[wv] = v;
    __syncthreads();
    if (threadIdx.x == 0) {
        float S = (red[0] + red[1]) + (red[2] + red[3]);
        float qlat = S / (float)BNC / (float)NN;
        out_scalars[0] = 0.25f * qlat;   // commit
        out_scalars[1] = qlat;           // qlat
    }
}

// ---------------------------------------------------------------------------
extern "C" void kernel_launch(void* const* d_in, const int* in_sizes, int n_in,
                              void* d_out, int out_size, void* d_ws, size_t ws_size,
                              hipStream_t stream) {
    (void)in_sizes; (void)n_in; (void)out_size; (void)ws_size;
    const float* f   = (const float*)d_in[0];   // [B, N, C]
    const float* emb = (const float*)d_in[1];   // [K, C]
    float* out = (float*)d_out;                 // f_hat [B*N*C] + 2 scalars

    float* ws      = (float*)d_ws;
    float* f_rest  = ws;                                   // BNC floats
    float* r2_pad  = f_rest + BNC;                         // 8192 (unused, layout keep)
    float* e_sq    = r2_pad + BB * NN;                     // K (0.5*|e|^2)
    float* slots   = e_sq + KK;                            // 256
    unsigned long long* packed_all = (unsigned long long*)(slots + 256);  // 512*136
    u16* rest_bf = (u16*)(packed_all + (size_t)BB * 136);  // 8192*256 bf16
    u16* emb_bf  = rest_bf + (size_t)BB * NN * CC;         // K*C bf16 (negated)

    float* f_hat = out;  // accumulate output in place

    hipMemsetAsync(out, 0, (size_t)BNC * sizeof(float), stream);
    hipMemcpyAsync(f_rest, f, (size_t)BNC * sizeof(float), hipMemcpyDeviceToDevice, stream);
    hipMemsetAsync(slots, 0, 256 * sizeof(float), stream);
    hipMemsetAsync(packed_all, 0xFF, (size_t)BB * 136 * sizeof(unsigned long long), stream);
    esq_kernel<<<KK / 4, 256, 0, stream>>>(emb, e_sq);
    cvt_emb_kernel<<<KK * CC / 4 / 256, 256, 0, stream>>>(emb, emb_bf);
    init_pool_kernel<<<BB, 256, 0, stream>>>(f, rest_bf);

    // splits per pn: blocks = 2*pn * splits in [256, 512]; cpb = 8192/splits
    // (cpb in {64,128,256,512}: sE fits 512 floats, chunks >= 8)
    static const int splits_tab[17] =
        {0,128,64,64,32,32,32,32,16,16,16,16,16,16,16,16,16};

    for (int pn = 1; pn <= NN; ++pn) {
        unsigned long long* packed = packed_all + (size_t)BB * (pn * (pn - 1) / 2);
        int splits = splits_tab[pn];
        int cpb = KK / splits;
        dim3 grid(BB * pn / 256, splits);
        dist_mfma_kernel<<<grid, 256, 0, stream>>>(rest_bf, emb_bf, e_sq, packed, cpb);
        update_pool_kernel<<<BB, 256, 0, stream>>>(f, emb, packed, f_rest, f_hat,
                                                   slots, rest_bf, pn);
    }
    final_kernel<<<1, 256, 0, stream>>>(slots, out + BNC);
}

// Round 6
// 768.260 us; speedup vs baseline: 1.0256x; 1.0256x over previous
//
#include <hip/hip_runtime.h>
#include <math.h>

#define BB 512
#define NN 16
#define CC 256
#define KK 8192
#define BNC (BB*NN*CC)

typedef unsigned short u16;
typedef __attribute__((ext_vector_type(8))) short bf16x8;
typedef __attribute__((ext_vector_type(4))) float f32x4;

__device__ __forceinline__ u16 f2bf(float x) {
    unsigned u = __float_as_uint(x);
    unsigned r = (u + 0x7fffu + ((u >> 16) & 1u)) >> 16;
    return (u16)r;
}

__device__ __forceinline__ void gl2lds16(const void* g, void* l) {
    __builtin_amdgcn_global_load_lds(
        (const __attribute__((address_space(1))) void*)g,
        (__attribute__((address_space(3))) void*)l,
        16, 0, 0);
}

__device__ __forceinline__ void gl2lds4(const void* g, void* l) {
    __builtin_amdgcn_global_load_lds(
        (const __attribute__((address_space(1))) void*)g,
        (__attribute__((address_space(3))) void*)l,
        4, 0, 0);
}

// ---------------------------------------------------------------------------
// stores 0.5*|e|^2 (folded into MFMA acc init in dist kernel)
__global__ void esq_kernel(const float* __restrict__ emb, float* __restrict__ e_sq) {
    int gid  = blockIdx.x * blockDim.x + threadIdx.x;
    int wave = gid >> 6;
    int lane = gid & 63;
    const float4 v = *(const float4*)(emb + (size_t)wave * CC + lane * 4);
    float s = v.x*v.x + v.y*v.y + v.z*v.z + v.w*v.w;
    #pragma unroll
    for (int m = 32; m >= 1; m >>= 1) s += __shfl_xor(s, m, 64);
    if (lane == 0) e_sq[wave] = 0.5f * s;
}

// stores NEGATED emb in bf16 so MFMA accumulates 0.5*esq - dot
__global__ void cvt_emb_kernel(const float* __restrict__ emb, u16* __restrict__ out) {
    int gid = blockIdx.x * blockDim.x + threadIdx.x;
    float4 v = ((const float4*)emb)[gid];
    ushort4 o;
    o.x = f2bf(-v.x); o.y = f2bf(-v.y); o.z = f2bf(-v.z); o.w = f2bf(-v.w);
    ((ushort4*)out)[gid] = o;
}

// initial pool for pn=1
__global__ void init_pool_kernel(const float* __restrict__ f,
                                 u16* __restrict__ rest_bf) {
    int b = blockIdx.x;
    int c = threadIdx.x;
    const float* base = f + (size_t)b * NN * CC + c;
    float acc = 0.f;
    #pragma unroll
    for (int n = 0; n < NN; ++n) acc += base[(size_t)n * CC];
    rest_bf[(size_t)b * CC + c] = f2bf(acc * (1.0f / 16.0f));
}

// ---------------------------------------------------------------------------
__device__ __forceinline__ unsigned long long shfl_xor_u64(unsigned long long v, int m) {
    unsigned lo = (unsigned)v, hi = (unsigned)(v >> 32);
    lo = __shfl_xor(lo, m, 64);
    hi = __shfl_xor(hi, m, 64);
    return ((unsigned long long)hi << 32) | lo;
}

// MFMA distance+argmin, v7 (2-barrier phase template, 2 chunks/phase):
//  - Block = 256 rows: wave w owns rows r0+w*64.., resident in regs bf[4][8].
//  - Codes staged into a block-shared 8-deep LDS ring (chunk = 64 codes x
//    64B K-slice = 4KB; 1 gl2lds16/thread/chunk), granule-XOR-swizzled via
//    pre-swizzled global source (v6-proven: 0 bank conflicts).
//  - Phase (2 chunks, 32 MFMAs):
//      pre-barrier:  STAGEC(t+6),STAGEC(t+7); ds_read cf for chunks t,t+1
//                    (latency overlaps barrier convergence + other waves)
//      barrier; lgkmcnt(0); sched_barrier(0)   [rule #18: stop MFMA hoist]
//      setprio(1); 32x MFMA; setprio(0)
//      vmcnt(4); barrier                        [counted, never 0]
//    Ring depth 8 => stage of t+6/7 overwrites bufs (t-2)&7/(t-1)&7, whose
//    reads retired before the previous second-barrier.
//  - Prologue issue order bf(32) -> esq(<=2) -> C0..C5; vmcnt(4) retires
//    bf+esq+C0+C1 (uniform literal), then one barrier into the loop.
//  - LDS 66KB keeps occupancy at 2 blocks/CU -> 256-VGPR budget (the fix
//    that ended v2/v3's spill-for-occupancy; verified v5/v6).
__global__ __launch_bounds__(256, 2) void dist_mfma_kernel(
        const u16* __restrict__ A, const u16* __restrict__ Bm,
        const float* __restrict__ e_sq,
        unsigned long long* __restrict__ packed, int cpb) {
    __shared__ __align__(16) u16 sC[32768];   // 64KB: first 32KB = 8-chunk ring; rest = occupancy pad
    __shared__ __align__(16) float sE[512];   // whole esq strip for this block
    const int tid = threadIdx.x;
    const int w = tid >> 6, l = tid & 63;
    const int r0 = blockIdx.x * 256;
    const int c0 = blockIdx.y * cpb;
    const int nch = cpb >> 3;    // 64B K-chunks
    const int ncb2 = cpb >> 6;   // 64-code blocks (4 phases each)
    const int arow = l & 15;
    const int aq   = l >> 4;

    // ---- resident row fragments (issued FIRST; retire first in vm FIFO) ----
    bf16x8 bf[4][8];
    {
        const u16* fb = A + (((size_t)(r0 + w * 64 + arow)) << 8) + aq * 8;
        #pragma unroll
        for (int j = 0; j < 4; ++j)
            #pragma unroll
            for (int kc = 0; kc < 8; ++kc)
                bf[j][kc] = *(const bf16x8*)(fb + (j << 12) + (kc << 5));
    }

    // ---- esq strip staged whole in prologue (cpb <= 512) ----
    for (int n = tid; n < cpb; n += 256)
        gl2lds4(e_sq + c0 + n, (char*)sE + (size_t)(n - l) * 4);

    // ---- code chunk staging (pre-swizzled source, linear LDS dest) ----
    const int crel = w * 16 + (l >> 2);
    const int g = (l & 3) ^ ((l >> 3) & 3);
    const u16* Pb = Bm + (((size_t)(c0 + crel)) << 8) + g * 8;

    #define STAGEC(t_) { \
        int tt_ = (t_); if (tt_ >= nch) tt_ = nch - 1; \
        const u16* s_ = Pb + (((size_t)(tt_ >> 3)) << 14) + ((tt_ & 7) << 5); \
        gl2lds16(s_, (char*)sC + (((t_) & 7) << 12) + (w << 10)); }

    STAGEC(0) STAGEC(1) STAGEC(2) STAGEC(3) STAGEC(4) STAGEC(5)

    const int gx = aq ^ ((arow >> 1) & 3);   // read-side granule swizzle
    float bestd[4];
    int   bestk[4];
    #pragma unroll
    for (int j = 0; j < 4; ++j) { bestd[j] = 1e30f; bestk[j] = 0; }

    // bf + esq + C0 + C1 retired; C2..C5 in flight
    asm volatile("s_waitcnt vmcnt(4)" ::: "memory");
    __builtin_amdgcn_s_barrier();

    for (int cb = 0; cb < ncb2; ++cb) {
        f32x4 acc[4][4];
        #pragma unroll
        for (int ph = 0; ph < 4; ++ph) {
            const int t0 = cb * 8 + ph * 2;
            // ---- pre-barrier zone: stage t0+6,t0+7; read cf for t0,t0+1 ----
            STAGEC(t0 + 6)
            STAGEC(t0 + 7)
            bf16x8 cf[2][4];
            #pragma unroll
            for (int h = 0; h < 2; ++h) {
                const u16* cbp = sC + (((t0 + h) & 7) << 11);
                #pragma unroll
                for (int i = 0; i < 4; ++i)
                    cf[h][i] = *(const bf16x8*)(cbp + ((i * 16 + arow) << 5) + (gx << 3));
            }
            f32x4 ev[4];
            if (ph == 0) {
                #pragma unroll
                for (int i = 0; i < 4; ++i)
                    ev[i] = *(const f32x4*)(sE + cb * 64 + i * 16 + (aq << 2));
            }
            // ---- barrier; drain own LDS reads; pin schedule ----
            __builtin_amdgcn_s_barrier();
            asm volatile("s_waitcnt lgkmcnt(0)" ::: "memory");
            __builtin_amdgcn_sched_barrier(0);
            if (ph == 0) {
                #pragma unroll
                for (int i = 0; i < 4; ++i)
                    #pragma unroll
                    for (int j = 0; j < 4; ++j) acc[i][j] = ev[i];
            }
            __builtin_amdgcn_s_setprio(1);
            #pragma unroll
            for (int h = 0; h < 2; ++h) {
                const int kc = ph * 2 + h;
                #pragma unroll
                for (int i = 0; i < 4; ++i)
                    #pragma unroll
                    for (int j = 0; j < 4; ++j)
                        acc[i][j] = __builtin_amdgcn_mfma_f32_16x16x32_bf16(
                                        cf[h][i], bf[j][kc], acc[i][j], 0, 0, 0);
            }
            __builtin_amdgcn_s_setprio(0);
            // ---- counted drain: chunks t0+2,t0+3 landed; 4 newest in flight ----
            asm volatile("s_waitcnt vmcnt(4)" ::: "memory");
            __builtin_amdgcn_s_barrier();
        }

        // fold: acc holds 0.5*d; argmin per f-row (j) over this cb's 16 codes/lane
        #pragma unroll
        for (int i = 0; i < 4; ++i)
            #pragma unroll
            for (int r = 0; r < 4; ++r) {
                const int k = c0 + cb * 64 + i * 16 + (aq << 2) + r;
                #pragma unroll
                for (int j = 0; j < 4; ++j) {
                    const float d = acc[i][j][r];
                    if (d < bestd[j]) { bestd[j] = d; bestk[j] = k; }
                }
            }
    }
    #undef STAGEC

    // merge across the 4 aq-lanes holding the same f-row, then global merge
    #pragma unroll
    for (int j = 0; j < 4; ++j) {
        unsigned u = __float_as_uint(bestd[j]);
        u = (u & 0x80000000u) ? ~u : (u | 0x80000000u);
        unsigned long long p = ((unsigned long long)u << 32) | (unsigned)bestk[j];
        unsigned long long o = shfl_xor_u64(p, 16);
        if (o < p) p = o;
        o = shfl_xor_u64(p, 32);
        if (o < p) p = o;
        if (aq == 0)
            atomicMin(&packed[r0 + w * 64 + j * 16 + arow], p);
    }
}

// ---------------------------------------------------------------------------
// Fused: gather + upsample + f_hat/f_rest update + qlat partial + pool for pn+1.
__global__ void update_pool_kernel(const float* __restrict__ f,
                                   const float* __restrict__ emb,
                                   const unsigned long long* __restrict__ packed,
                                   float* __restrict__ f_rest,
                                   float* __restrict__ f_hat,
                                   float* __restrict__ slots,
                                   u16* __restrict__ rest_bf, int pn) {
    int b = blockIdx.x;
    int c = threadIdx.x;
    __shared__ int sk[NN];
    __shared__ float red[4];
    if (threadIdx.x < pn)
        sk[threadIdx.x] = (int)(unsigned)(packed[b * pn + threadIdx.x] & 0xffffffffull);
    __syncthreads();

    float fr[NN];
    float acc_sq = 0.f;
    #pragma unroll
    for (int n = 0; n < NN; ++n) {
        double pos = (n + 0.5) * ((double)pn / 16.0) - 0.5;
        if (pos < 0.0) pos = 0.0;
        int i0 = (int)floor(pos);
        if (i0 > pn - 1) i0 = pn - 1;
        int i1 = i0 + 1;
        if (i1 > pn - 1) i1 = pn - 1;
        double frac = pos - (double)i0;
        float w1 = (float)frac;
        float w0 = (float)(1.0 - frac);
        float h = w0 * emb[(size_t)sk[i0] * CC + c] + w1 * emb[(size_t)sk[i1] * CC + c];
        size_t off = ((size_t)b * NN + n) * CC + c;
        float fh = f_hat[off] + h;
        f_hat[off] = fh;
        float fre = f_rest[off] - h;
        f_rest[off] = fre;
        fr[n] = fre;
        float diff = fh - f[off];
        acc_sq += diff * diff;
    }

    int wv = threadIdx.x >> 6, ln = threadIdx.x & 63;
    #pragma unroll
    for (int m = 32; m >= 1; m >>= 1) acc_sq += __shfl_xor(acc_sq, m, 64);
    if (ln == 0) red[wv] = acc_sq;

    int pn2 = pn + 1;
    if (pn < NN) {
        for (int p = 0; p < pn2; ++p) {
            int s = (p * NN) / pn2;
            int e = ((p + 1) * NN + pn2 - 1) / pn2;
            float v = 0.f;
            for (int n = s; n < e; ++n) v += fr[n];
            v *= 1.0f / (float)(e - s);
            rest_bf[((size_t)(b * pn2 + p)) * CC + c] = f2bf(v);
        }
    }
    __syncthreads();
    if (threadIdx.x == 0)
        atomicAdd(&slots[b & 255], (red[0] + red[1]) + (red[2] + red[3]));
}

// ---------------------------------------------------------------------------
__global__ void final_kernel(const float* __restrict__ slots, float* __restrict__ out_scalars) {
    float v = slots[threadIdx.x];
    #pragma unroll
    for (int m = 32; m >= 1; m >>= 1) v += __shfl_xor(v, m, 64);
    __shared__ float red[4];
    int wv = threadIdx.x >> 6, ln = threadIdx.x & 63;
    if (ln == 0) red[wv] = v;
    __syncthreads();
    if (threadIdx.x == 0) {
        float S = (red[0] + red[1]) + (red[2] + red[3]);
        float qlat = S / (float)BNC / (float)NN;
        out_scalars[0] = 0.25f * qlat;   // commit
        out_scalars[1] = qlat;           // qlat
    }
}

// ---------------------------------------------------------------------------
extern "C" void kernel_launch(void* const* d_in, const int* in_sizes, int n_in,
                              void* d_out, int out_size, void* d_ws, size_t ws_size,
                              hipStream_t stream) {
    (void)in_sizes; (void)n_in; (void)out_size; (void)ws_size;
    const float* f   = (const float*)d_in[0];   // [B, N, C]
    const float* emb = (const float*)d_in[1];   // [K, C]
    float* out = (float*)d_out;                 // f_hat [B*N*C] + 2 scalars

    float* ws      = (float*)d_ws;
    float* f_rest  = ws;                                   // BNC floats
    float* r2_pad  = f_rest + BNC;                         // 8192 (unused, layout keep)
    float* e_sq    = r2_pad + BB * NN;                     // K (0.5*|e|^2)
    float* slots   = e_sq + KK;                            // 256
    unsigned long long* packed_all = (unsigned long long*)(slots + 256);  // 512*136
    u16* rest_bf = (u16*)(packed_all + (size_t)BB * 136);  // 8192*256 bf16
    u16* emb_bf  = rest_bf + (size_t)BB * NN * CC;         // K*C bf16 (negated)

    float* f_hat = out;  // accumulate output in place

    hipMemsetAsync(out, 0, (size_t)BNC * sizeof(float), stream);
    hipMemcpyAsync(f_rest, f, (size_t)BNC * sizeof(float), hipMemcpyDeviceToDevice, stream);
    hipMemsetAsync(slots, 0, 256 * sizeof(float), stream);
    hipMemsetAsync(packed_all, 0xFF, (size_t)BB * 136 * sizeof(unsigned long long), stream);
    esq_kernel<<<KK / 4, 256, 0, stream>>>(emb, e_sq);
    cvt_emb_kernel<<<KK * CC / 4 / 256, 256, 0, stream>>>(emb, emb_bf);
    init_pool_kernel<<<BB, 256, 0, stream>>>(f, rest_bf);

    // splits: target >= 512 blocks (2/CU) where cpb >= 64 allows; cpb = 8192/splits
    static const int splits_tab[17] =
        {0,128,128,128,64,64,64,64,32,32,32,32,32,32,32,32,16};

    for (int pn = 1; pn <= NN; ++pn) {
        unsigned long long* packed = packed_all + (size_t)BB * (pn * (pn - 1) / 2);
        int splits = splits_tab[pn];
        int cpb = KK / splits;
        dim3 grid(BB * pn / 256, splits);
        dist_mfma_kernel<<<grid, 256, 0, stream>>>(rest_bf, emb_bf, e_sq, packed, cpb);
        update_pool_kernel<<<BB, 256, 0, stream>>>(f, emb, packed, f_rest, f_hat,
                                                   slots, rest_bf, pn);
    }
    final_kernel<<<1, 256, 0, stream>>>(slots, out + BNC);
}

// Round 7
// 722.422 us; speedup vs baseline: 1.0907x; 1.0635x over previous
//
#include <hip/hip_runtime.h>
#include <math.h>

#define BB 512
#define NN 16
#define CC 256
#define KK 8192
#define BNC (BB*NN*CC)

typedef unsigned short u16;
typedef __attribute__((ext_vector_type(8))) short bf16x8;
typedef __attribute__((ext_vector_type(4))) float f32x4;

__device__ __forceinline__ u16 f2bf(float x) {
    unsigned u = __float_as_uint(x);
    unsigned r = (u + 0x7fffu + ((u >> 16) & 1u)) >> 16;
    return (u16)r;
}

__device__ __forceinline__ void gl2lds16(const void* g, void* l) {
    __builtin_amdgcn_global_load_lds(
        (const __attribute__((address_space(1))) void*)g,
        (__attribute__((address_space(3))) void*)l,
        16, 0, 0);
}

__device__ __forceinline__ void gl2lds4(const void* g, void* l) {
    __builtin_amdgcn_global_load_lds(
        (const __attribute__((address_space(1))) void*)g,
        (__attribute__((address_space(3))) void*)l,
        4, 0, 0);
}

// ---------------------------------------------------------------------------
// stores 0.5*|e|^2 (folded into MFMA acc init in dist kernel)
__global__ void esq_kernel(const float* __restrict__ emb, float* __restrict__ e_sq) {
    int gid  = blockIdx.x * blockDim.x + threadIdx.x;
    int wave = gid >> 6;
    int lane = gid & 63;
    const float4 v = *(const float4*)(emb + (size_t)wave * CC + lane * 4);
    float s = v.x*v.x + v.y*v.y + v.z*v.z + v.w*v.w;
    #pragma unroll
    for (int m = 32; m >= 1; m >>= 1) s += __shfl_xor(s, m, 64);
    if (lane == 0) e_sq[wave] = 0.5f * s;
}

// stores NEGATED emb in bf16 so MFMA accumulates 0.5*esq - dot
__global__ void cvt_emb_kernel(const float* __restrict__ emb, u16* __restrict__ out) {
    int gid = blockIdx.x * blockDim.x + threadIdx.x;
    float4 v = ((const float4*)emb)[gid];
    ushort4 o;
    o.x = f2bf(-v.x); o.y = f2bf(-v.y); o.z = f2bf(-v.z); o.w = f2bf(-v.w);
    ((ushort4*)out)[gid] = o;
}

// initial pool for pn=1
__global__ void init_pool_kernel(const float* __restrict__ f,
                                 u16* __restrict__ rest_bf) {
    int b = blockIdx.x;
    int c = threadIdx.x;
    const float* base = f + (size_t)b * NN * CC + c;
    float acc = 0.f;
    #pragma unroll
    for (int n = 0; n < NN; ++n) acc += base[(size_t)n * CC];
    rest_bf[(size_t)b * CC + c] = f2bf(acc * (1.0f / 16.0f));
}

// ---------------------------------------------------------------------------
__device__ __forceinline__ unsigned long long shfl_xor_u64(unsigned long long v, int m) {
    unsigned lo = (unsigned)v, hi = (unsigned)(v >> 32);
    lo = __shfl_xor(lo, m, 64);
    hi = __shfl_xor(hi, m, 64);
    return ((unsigned long long)hi << 32) | lo;
}

// MFMA distance+argmin, v8 (cb-level double buffer; 1 barrier per 128 MFMAs):
//  - Block = 256 rows: wave w owns rows r0+w*64.., resident in regs bf[4][8].
//  - Codes staged per 64-code cb-group (32KB = 8 chunks x 4KB) into a
//    2-deep cb-level double buffer, granule-XOR-swizzled via pre-swizzled
//    global source (v6-proven: 0 bank conflicts).
//  - Per cb: burst-issue all 8 next-cb stages right after the barrier
//    (~1200 cyc of flight >> L2 latency), then compute 8 chunks (4 ds_read
//    + 16 MFMA each) with NO intra-cb syncs -> waves drift freely and the
//    2 co-resident blocks' waves anti-align on the SIMDs (m114 overlap),
//    then fold, vmcnt(0) [own stages done], ONE barrier [all waves' stages
//    done -> cb+1 fully resident; all reads of this buffer retired].
//    Sync density: 1 barrier + 1 vmcnt per 128 MFMAs (v6: 2+1 per 16).
//  - esq strip staged whole in prologue; acc init = f32x4 LDS broadcast.
//  - LDS 66KB keeps occupancy at 2 blocks/CU -> 256-VGPR budget (the fix
//    that ended v2/v3's spill-for-occupancy; verified v5-v7: no spill).
__global__ __launch_bounds__(256, 2) void dist_mfma_kernel(
        const u16* __restrict__ A, const u16* __restrict__ Bm,
        const float* __restrict__ e_sq,
        unsigned long long* __restrict__ packed, int cpb) {
    __shared__ __align__(16) u16 sC[32768];   // 64KB: 2 cb-buffers x 32KB
    __shared__ __align__(16) float sE[512];   // whole esq strip for this block
    const int tid = threadIdx.x;
    const int w = tid >> 6, l = tid & 63;
    const int r0 = blockIdx.x * 256;
    const int c0 = blockIdx.y * cpb;
    const int ncb2 = cpb >> 6;   // 64-code cb-groups
    const int arow = l & 15;
    const int aq   = l >> 4;

    // ---- resident row fragments ----
    bf16x8 bf[4][8];
    {
        const u16* fb = A + (((size_t)(r0 + w * 64 + arow)) << 8) + aq * 8;
        #pragma unroll
        for (int j = 0; j < 4; ++j)
            #pragma unroll
            for (int kc = 0; kc < 8; ++kc)
                bf[j][kc] = *(const bf16x8*)(fb + (j << 12) + (kc << 5));
    }

    // ---- esq strip staged whole in prologue (cpb <= 512) ----
    for (int n = tid; n < cpb; n += 256)
        gl2lds4(e_sq + c0 + n, (char*)sE + (size_t)(n - l) * 4);

    // ---- code staging mapping (pre-swizzled source, linear LDS dest) ----
    // thread covers slot s = w*64+l of each 4KB chunk: code crel = s>>2,
    // stored granule (s&3) receives actual granule g = (s&3)^((s>>3)&3).
    const int crel = w * 16 + (l >> 2);
    const int g = (l & 3) ^ ((l >> 3) & 3);
    const u16* Pb = Bm + (((size_t)(c0 + crel)) << 8) + g * 8;

    // stage all 8 chunks of cb-group cb_ into buffer (cb_&1)
    #define STAGE_CB(cb_) { \
        const u16* s0_ = Pb + ((size_t)(cb_) << 14); \
        char* d0_ = (char*)sC + (((cb_) & 1) << 15) + (w << 10); \
        _Pragma("unroll") \
        for (int c_ = 0; c_ < 8; ++c_) \
            gl2lds16(s0_ + (c_ << 5), d0_ + (c_ << 12)); }

    STAGE_CB(0)

    const int gx = aq ^ ((arow >> 1) & 3);   // read-side granule swizzle
    float bestd[4];
    int   bestk[4];
    #pragma unroll
    for (int j = 0; j < 4; ++j) { bestd[j] = 1e30f; bestk[j] = 0; }

    asm volatile("s_waitcnt vmcnt(0)" ::: "memory");
    __builtin_amdgcn_s_barrier();
    asm volatile("" ::: "memory");

    for (int cb = 0; cb < ncb2; ++cb) {
        // burst-issue next cb's stages (max flight time before the drain)
        if (cb + 1 < ncb2) STAGE_CB(cb + 1)

        f32x4 acc[4][4];
        #pragma unroll
        for (int i = 0; i < 4; ++i) {
            f32x4 ev = *(const f32x4*)(sE + cb * 64 + i * 16 + (aq << 2));
            #pragma unroll
            for (int j = 0; j < 4; ++j) acc[i][j] = ev;
        }

        const u16* bufp = sC + ((cb & 1) << 14);   // u16 units: 32KB buffer
        #pragma unroll
        for (int c = 0; c < 8; ++c) {
            bf16x8 cf[4];
            const u16* cbp = bufp + (c << 11);
            #pragma unroll
            for (int i = 0; i < 4; ++i)
                cf[i] = *(const bf16x8*)(cbp + ((i * 16 + arow) << 5) + (gx << 3));
            __builtin_amdgcn_s_setprio(1);
            #pragma unroll
            for (int i = 0; i < 4; ++i)
                #pragma unroll
                for (int j = 0; j < 4; ++j)
                    acc[i][j] = __builtin_amdgcn_mfma_f32_16x16x32_bf16(
                                    cf[i], bf[j][c], acc[i][j], 0, 0, 0);
            __builtin_amdgcn_s_setprio(0);
        }

        // fold (register-only; overlaps tail of in-flight stages)
        #pragma unroll
        for (int i = 0; i < 4; ++i)
            #pragma unroll
            for (int r = 0; r < 4; ++r) {
                const int k = c0 + cb * 64 + i * 16 + (aq << 2) + r;
                #pragma unroll
                for (int j = 0; j < 4; ++j) {
                    const float d = acc[i][j][r];
                    if (d < bestd[j]) { bestd[j] = d; bestk[j] = k; }
                }
            }

        // own stages for cb+1 complete; reads of this buffer retired
        asm volatile("s_waitcnt vmcnt(0) lgkmcnt(0)" ::: "memory");
        __builtin_amdgcn_s_barrier();
        asm volatile("" ::: "memory");
    }
    #undef STAGE_CB

    // merge across the 4 aq-lanes holding the same f-row, then global merge
    #pragma unroll
    for (int j = 0; j < 4; ++j) {
        unsigned u = __float_as_uint(bestd[j]);
        u = (u & 0x80000000u) ? ~u : (u | 0x80000000u);
        unsigned long long p = ((unsigned long long)u << 32) | (unsigned)bestk[j];
        unsigned long long o = shfl_xor_u64(p, 16);
        if (o < p) p = o;
        o = shfl_xor_u64(p, 32);
        if (o < p) p = o;
        if (aq == 0)
            atomicMin(&packed[r0 + w * 64 + j * 16 + arow], p);
    }
}

// ---------------------------------------------------------------------------
// Fused: gather + upsample + f_hat/f_rest update + qlat partial + pool for pn+1.
__global__ void update_pool_kernel(const float* __restrict__ f,
                                   const float* __restrict__ emb,
                                   const unsigned long long* __restrict__ packed,
                                   float* __restrict__ f_rest,
                                   float* __restrict__ f_hat,
                                   float* __restrict__ slots,
                                   u16* __restrict__ rest_bf, int pn) {
    int b = blockIdx.x;
    int c = threadIdx.x;
    __shared__ int sk[NN];
    __shared__ float red[4];
    if (threadIdx.x < pn)
        sk[threadIdx.x] = (int)(unsigned)(packed[b * pn + threadIdx.x] & 0xffffffffull);
    __syncthreads();

    float fr[NN];
    float acc_sq = 0.f;
    #pragma unroll
    for (int n = 0; n < NN; ++n) {
        double pos = (n + 0.5) * ((double)pn / 16.0) - 0.5;
        if (pos < 0.0) pos = 0.0;
        int i0 = (int)floor(pos);
        if (i0 > pn - 1) i0 = pn - 1;
        int i1 = i0 + 1;
        if (i1 > pn - 1) i1 = pn - 1;
        double frac = pos - (double)i0;
        float w1 = (float)frac;
        float w0 = (float)(1.0 - frac);
        float h = w0 * emb[(size_t)sk[i0] * CC + c] + w1 * emb[(size_t)sk[i1] * CC + c];
        size_t off = ((size_t)b * NN + n) * CC + c;
        float fh = f_hat[off] + h;
        f_hat[off] = fh;
        float fre = f_rest[off] - h;
        f_rest[off] = fre;
        fr[n] = fre;
        float diff = fh - f[off];
        acc_sq += diff * diff;
    }

    int wv = threadIdx.x >> 6, ln = threadIdx.x & 63;
    #pragma unroll
    for (int m = 32; m >= 1; m >>= 1) acc_sq += __shfl_xor(acc_sq, m, 64);
    if (ln == 0) red[wv] = acc_sq;

    int pn2 = pn + 1;
    if (pn < NN) {
        for (int p = 0; p < pn2; ++p) {
            int s = (p * NN) / pn2;
            int e = ((p + 1) * NN + pn2 - 1) / pn2;
            float v = 0.f;
            for (int n = s; n < e; ++n) v += fr[n];
            v *= 1.0f / (float)(e - s);
            rest_bf[((size_t)(b * pn2 + p)) * CC + c] = f2bf(v);
        }
    }
    __syncthreads();
    if (threadIdx.x == 0)
        atomicAdd(&slots[b & 255], (red[0] + red[1]) + (red[2] + red[3]));
}

// ---------------------------------------------------------------------------
__global__ void final_kernel(const float* __restrict__ slots, float* __restrict__ out_scalars) {
    float v = slots[threadIdx.x];
    #pragma unroll
    for (int m = 32; m >= 1; m >>= 1) v += __shfl_xor(v, m, 64);
    __shared__ float red[4];
    int wv = threadIdx.x >> 6, ln = threadIdx.x & 63;
    if (ln == 0) red[wv] = v;
    __syncthreads();
    if (threadIdx.x == 0) {
        float S = (red[0] + red[1]) + (red[2] + red[3]);
        float qlat = S / (float)BNC / (float)NN;
        out_scalars[0] = 0.25f * qlat;   // commit
        out_scalars[1] = qlat;           // qlat
    }
}

// ---------------------------------------------------------------------------
extern "C" void kernel_launch(void* const* d_in, const int* in_sizes, int n_in,
                              void* d_out, int out_size, void* d_ws, size_t ws_size,
                              hipStream_t stream) {
    (void)in_sizes; (void)n_in; (void)out_size; (void)ws_size;
    const float* f   = (const float*)d_in[0];   // [B, N, C]
    const float* emb = (const float*)d_in[1];   // [K, C]
    float* out = (float*)d_out;                 // f_hat [B*N*C] + 2 scalars

    float* ws      = (float*)d_ws;
    float* f_rest  = ws;                                   // BNC floats
    float* r2_pad  = f_rest + BNC;                         // 8192 (unused, layout keep)
    float* e_sq    = r2_pad + BB * NN;                     // K (0.5*|e|^2)
    float* slots   = e_sq + KK;                            // 256
    unsigned long long* packed_all = (unsigned long long*)(slots + 256);  // 512*136
    u16* rest_bf = (u16*)(packed_all + (size_t)BB * 136);  // 8192*256 bf16
    u16* emb_bf  = rest_bf + (size_t)BB * NN * CC;         // K*C bf16 (negated)

    float* f_hat = out;  // accumulate output in place

    hipMemsetAsync(out, 0, (size_t)BNC * sizeof(float), stream);
    hipMemcpyAsync(f_rest, f, (size_t)BNC * sizeof(float), hipMemcpyDeviceToDevice, stream);
    hipMemsetAsync(slots, 0, 256 * sizeof(float), stream);
    hipMemsetAsync(packed_all, 0xFF, (size_t)BB * 136 * sizeof(unsigned long long), stream);
    esq_kernel<<<KK / 4, 256, 0, stream>>>(emb, e_sq);
    cvt_emb_kernel<<<KK * CC / 4 / 256, 256, 0, stream>>>(emb, emb_bf);
    init_pool_kernel<<<BB, 256, 0, stream>>>(f, rest_bf);

    // splits: target >= 512 blocks where cpb >= 64 allows; cpb = 8192/splits
    static const int splits_tab[17] =
        {0,128,128,128,64,64,64,64,32,32,32,32,32,32,32,32,16};

    for (int pn = 1; pn <= NN; ++pn) {
        unsigned long long* packed = packed_all + (size_t)BB * (pn * (pn - 1) / 2);
        int splits = splits_tab[pn];
        int cpb = KK / splits;
        dim3 grid(BB * pn / 256, splits);
        dist_mfma_kernel<<<grid, 256, 0, stream>>>(rest_bf, emb_bf, e_sq, packed, cpb);
        update_pool_kernel<<<BB, 256, 0, stream>>>(f, emb, packed, f_rest, f_hat,
                                                   slots, rest_bf, pn);
    }
    final_kernel<<<1, 256, 0, stream>>>(slots, out + BNC);
}

// Round 8
// 717.275 us; speedup vs baseline: 1.0985x; 1.0072x over previous
//
#include <hip/hip_runtime.h>
#include <math.h>

#define BB 512
#define NN 16
#define CC 256
#define KK 8192
#define BNC (BB*NN*CC)

typedef unsigned short u16;
typedef __attribute__((ext_vector_type(8))) short bf16x8;
typedef __attribute__((ext_vector_type(4))) float f32x4;

__device__ __forceinline__ u16 f2bf(float x) {
    unsigned u = __float_as_uint(x);
    unsigned r = (u + 0x7fffu + ((u >> 16) & 1u)) >> 16;
    return (u16)r;
}

__device__ __forceinline__ void gl2lds16(const void* g, void* l) {
    __builtin_amdgcn_global_load_lds(
        (const __attribute__((address_space(1))) void*)g,
        (__attribute__((address_space(3))) void*)l,
        16, 0, 0);
}

__device__ __forceinline__ void gl2lds4(const void* g, void* l) {
    __builtin_amdgcn_global_load_lds(
        (const __attribute__((address_space(1))) void*)g,
        (__attribute__((address_space(3))) void*)l,
        4, 0, 0);
}

// ---------------------------------------------------------------------------
// stores 0.5*|e|^2 (folded into MFMA acc init in dist kernel)
__global__ void esq_kernel(const float* __restrict__ emb, float* __restrict__ e_sq) {
    int gid  = blockIdx.x * blockDim.x + threadIdx.x;
    int wave = gid >> 6;
    int lane = gid & 63;
    const float4 v = *(const float4*)(emb + (size_t)wave * CC + lane * 4);
    float s = v.x*v.x + v.y*v.y + v.z*v.z + v.w*v.w;
    #pragma unroll
    for (int m = 32; m >= 1; m >>= 1) s += __shfl_xor(s, m, 64);
    if (lane == 0) e_sq[wave] = 0.5f * s;
}

// stores NEGATED emb in bf16 so MFMA accumulates 0.5*esq - dot
__global__ void cvt_emb_kernel(const float* __restrict__ emb, u16* __restrict__ out) {
    int gid = blockIdx.x * blockDim.x + threadIdx.x;
    float4 v = ((const float4*)emb)[gid];
    ushort4 o;
    o.x = f2bf(-v.x); o.y = f2bf(-v.y); o.z = f2bf(-v.z); o.w = f2bf(-v.w);
    ((ushort4*)out)[gid] = o;
}

// initial pool for pn=1
__global__ void init_pool_kernel(const float* __restrict__ f,
                                 u16* __restrict__ rest_bf) {
    int b = blockIdx.x;
    int c = threadIdx.x;
    const float* base = f + (size_t)b * NN * CC + c;
    float acc = 0.f;
    #pragma unroll
    for (int n = 0; n < NN; ++n) acc += base[(size_t)n * CC];
    rest_bf[(size_t)b * CC + c] = f2bf(acc * (1.0f / 16.0f));
}

// ---------------------------------------------------------------------------
__device__ __forceinline__ unsigned long long shfl_xor_u64(unsigned long long v, int m) {
    unsigned lo = (unsigned)v, hi = (unsigned)(v >> 32);
    lo = __shfl_xor(lo, m, 64);
    hi = __shfl_xor(hi, m, 64);
    return ((unsigned long long)hi << 32) | lo;
}

// MFMA distance+argmin, v9 (register diet: 32 rows/wave, 2 blocks/CU real):
//  v8 post-mortem: bf[4][8](128) + acc(64) pushed total regs/wave to ~300
//  (acc+bf in AGPRs, unified file) -> only ONE 4-wave block resident/CU
//  (~16% occupancy measured) -> latency-starved at ~43us regardless of
//  sync structure. Fix: wave owns 32 rows (bf[2][8]=64 VGPR), acc[4][2]=32,
//  total ~140 regs -> 2 blocks (8 waves)/CU genuinely fit.
//  - Block = 128 rows; codes staged per 64-code cb-group (32KB = 8 x 4KB)
//    into a 2-deep double buffer (shared by all 4 waves; gx-swizzled via
//    pre-swizzled global source -> 0 bank conflicts, proven v6-v8).
//  - Per cb: burst-issue next cb's 8 stages, compute 8 chunks (4 ds_read +
//    8 MFMA each, no intra-cb syncs), fold, vmcnt(0)+barrier (1 per cb).
//  - No setprio (v7: regressed), no sched_barrier(0) (m141).
//  - LDS 66KB caps at 2 blocks/CU; VGPR no longer the binding constraint.
__global__ __launch_bounds__(256, 2) void dist_mfma_kernel(
        const u16* __restrict__ A, const u16* __restrict__ Bm,
        const float* __restrict__ e_sq,
        unsigned long long* __restrict__ packed, int cpb) {
    __shared__ __align__(16) u16 sC[32768];   // 64KB: 2 cb-buffers x 32KB
    __shared__ __align__(16) float sE[512];   // whole esq strip for this block
    const int tid = threadIdx.x;
    const int w = tid >> 6, l = tid & 63;
    const int r0 = blockIdx.x * 128;
    const int c0 = blockIdx.y * cpb;
    const int ncb2 = cpb >> 6;   // 64-code cb-groups
    const int arow = l & 15;
    const int aq   = l >> 4;

    // ---- resident row fragments: wave owns rows r0+w*32 .. +31 ----
    bf16x8 bf[2][8];
    {
        const u16* fb = A + (((size_t)(r0 + w * 32 + arow)) << 8) + aq * 8;
        #pragma unroll
        for (int j = 0; j < 2; ++j)
            #pragma unroll
            for (int kc = 0; kc < 8; ++kc)
                bf[j][kc] = *(const bf16x8*)(fb + (j << 12) + (kc << 5));
    }

    // ---- esq strip staged whole in prologue (cpb <= 512) ----
    for (int n = tid; n < cpb; n += 256)
        gl2lds4(e_sq + c0 + n, (char*)sE + (size_t)(n - l) * 4);

    // ---- code staging mapping (pre-swizzled source, linear LDS dest) ----
    // thread covers slot s = w*64+l of each 4KB chunk: code crel = s>>2,
    // stored granule (s&3) receives actual granule g = (s&3)^((s>>3)&3).
    const int crel = w * 16 + (l >> 2);
    const int g = (l & 3) ^ ((l >> 3) & 3);
    const u16* Pb = Bm + (((size_t)(c0 + crel)) << 8) + g * 8;

    // stage all 8 chunks of cb-group cb_ into buffer (cb_&1)
    #define STAGE_CB(cb_) { \
        const u16* s0_ = Pb + ((size_t)(cb_) << 14); \
        char* d0_ = (char*)sC + (((cb_) & 1) << 15) + (w << 10); \
        _Pragma("unroll") \
        for (int c_ = 0; c_ < 8; ++c_) \
            gl2lds16(s0_ + (c_ << 5), d0_ + (c_ << 12)); }

    STAGE_CB(0)

    const int gx = aq ^ ((arow >> 1) & 3);   // read-side granule swizzle
    float bestd[2];
    int   bestk[2];
    #pragma unroll
    for (int j = 0; j < 2; ++j) { bestd[j] = 1e30f; bestk[j] = 0; }

    asm volatile("s_waitcnt vmcnt(0)" ::: "memory");
    __builtin_amdgcn_s_barrier();
    asm volatile("" ::: "memory");

    for (int cb = 0; cb < ncb2; ++cb) {
        // burst-issue next cb's stages (max flight time before the drain)
        if (cb + 1 < ncb2) STAGE_CB(cb + 1)

        f32x4 acc[4][2];
        #pragma unroll
        for (int i = 0; i < 4; ++i) {
            f32x4 ev = *(const f32x4*)(sE + cb * 64 + i * 16 + (aq << 2));
            #pragma unroll
            for (int j = 0; j < 2; ++j) acc[i][j] = ev;
        }

        const u16* bufp = sC + ((cb & 1) << 14);   // u16 units: 32KB buffer
        #pragma unroll
        for (int c = 0; c < 8; ++c) {
            bf16x8 cf[4];
            const u16* cbp = bufp + (c << 11);
            #pragma unroll
            for (int i = 0; i < 4; ++i)
                cf[i] = *(const bf16x8*)(cbp + ((i * 16 + arow) << 5) + (gx << 3));
            #pragma unroll
            for (int i = 0; i < 4; ++i)
                #pragma unroll
                for (int j = 0; j < 2; ++j)
                    acc[i][j] = __builtin_amdgcn_mfma_f32_16x16x32_bf16(
                                    cf[i], bf[j][c], acc[i][j], 0, 0, 0);
        }

        // fold (register-only; overlaps tail of in-flight stages)
        #pragma unroll
        for (int i = 0; i < 4; ++i)
            #pragma unroll
            for (int r = 0; r < 4; ++r) {
                const int k = c0 + cb * 64 + i * 16 + (aq << 2) + r;
                #pragma unroll
                for (int j = 0; j < 2; ++j) {
                    const float d = acc[i][j][r];
                    if (d < bestd[j]) { bestd[j] = d; bestk[j] = k; }
                }
            }

        // own stages for cb+1 complete; reads of this buffer retired
        asm volatile("s_waitcnt vmcnt(0) lgkmcnt(0)" ::: "memory");
        __builtin_amdgcn_s_barrier();
        asm volatile("" ::: "memory");
    }
    #undef STAGE_CB

    // merge across the 4 aq-lanes holding the same f-row, then global merge
    #pragma unroll
    for (int j = 0; j < 2; ++j) {
        unsigned u = __float_as_uint(bestd[j]);
        u = (u & 0x80000000u) ? ~u : (u | 0x80000000u);
        unsigned long long p = ((unsigned long long)u << 32) | (unsigned)bestk[j];
        unsigned long long o = shfl_xor_u64(p, 16);
        if (o < p) p = o;
        o = shfl_xor_u64(p, 32);
        if (o < p) p = o;
        if (aq == 0)
            atomicMin(&packed[r0 + w * 32 + j * 16 + arow], p);
    }
}

// ---------------------------------------------------------------------------
// Fused: gather + upsample + f_hat/f_rest update + qlat partial + pool for pn+1.
__global__ void update_pool_kernel(const float* __restrict__ f,
                                   const float* __restrict__ emb,
                                   const unsigned long long* __restrict__ packed,
                                   float* __restrict__ f_rest,
                                   float* __restrict__ f_hat,
                                   float* __restrict__ slots,
                                   u16* __restrict__ rest_bf, int pn) {
    int b = blockIdx.x;
    int c = threadIdx.x;
    __shared__ int sk[NN];
    __shared__ float red[4];
    if (threadIdx.x < pn)
        sk[threadIdx.x] = (int)(unsigned)(packed[b * pn + threadIdx.x] & 0xffffffffull);
    __syncthreads();

    float fr[NN];
    float acc_sq = 0.f;
    #pragma unroll
    for (int n = 0; n < NN; ++n) {
        double pos = (n + 0.5) * ((double)pn / 16.0) - 0.5;
        if (pos < 0.0) pos = 0.0;
        int i0 = (int)floor(pos);
        if (i0 > pn - 1) i0 = pn - 1;
        int i1 = i0 + 1;
        if (i1 > pn - 1) i1 = pn - 1;
        double frac = pos - (double)i0;
        float w1 = (float)frac;
        float w0 = (float)(1.0 - frac);
        float h = w0 * emb[(size_t)sk[i0] * CC + c] + w1 * emb[(size_t)sk[i1] * CC + c];
        size_t off = ((size_t)b * NN + n) * CC + c;
        float fh = f_hat[off] + h;
        f_hat[off] = fh;
        float fre = f_rest[off] - h;
        f_rest[off] = fre;
        fr[n] = fre;
        float diff = fh - f[off];
        acc_sq += diff * diff;
    }

    int wv = threadIdx.x >> 6, ln = threadIdx.x & 63;
    #pragma unroll
    for (int m = 32; m >= 1; m >>= 1) acc_sq += __shfl_xor(acc_sq, m, 64);
    if (ln == 0) red[wv] = acc_sq;

    int pn2 = pn + 1;
    if (pn < NN) {
        for (int p = 0; p < pn2; ++p) {
            int s = (p * NN) / pn2;
            int e = ((p + 1) * NN + pn2 - 1) / pn2;
            float v = 0.f;
            for (int n = s; n < e; ++n) v += fr[n];
            v *= 1.0f / (float)(e - s);
            rest_bf[((size_t)(b * pn2 + p)) * CC + c] = f2bf(v);
        }
    }
    __syncthreads();
    if (threadIdx.x == 0)
        atomicAdd(&slots[b & 255], (red[0] + red[1]) + (red[2] + red[3]));
}

// ---------------------------------------------------------------------------
__global__ void final_kernel(const float* __restrict__ slots, float* __restrict__ out_scalars) {
    float v = slots[threadIdx.x];
    #pragma unroll
    for (int m = 32; m >= 1; m >>= 1) v += __shfl_xor(v, m, 64);
    __shared__ float red[4];
    int wv = threadIdx.x >> 6, ln = threadIdx.x & 63;
    if (ln == 0) red[wv] = v;
    __syncthreads();
    if (threadIdx.x == 0) {
        float S = (red[0] + red[1]) + (red[2] + red[3]);
        float qlat = S / (float)BNC / (float)NN;
        out_scalars[0] = 0.25f * qlat;   // commit
        out_scalars[1] = qlat;           // qlat
    }
}

// ---------------------------------------------------------------------------
extern "C" void kernel_launch(void* const* d_in, const int* in_sizes, int n_in,
                              void* d_out, int out_size, void* d_ws, size_t ws_size,
                              hipStream_t stream) {
    (void)in_sizes; (void)n_in; (void)out_size; (void)ws_size;
    const float* f   = (const float*)d_in[0];   // [B, N, C]
    const float* emb = (const float*)d_in[1];   // [K, C]
    float* out = (float*)d_out;                 // f_hat [B*N*C] + 2 scalars

    float* ws      = (float*)d_ws;
    float* f_rest  = ws;                                   // BNC floats
    float* r2_pad  = f_rest + BNC;                         // 8192 (unused, layout keep)
    float* e_sq    = r2_pad + BB * NN;                     // K (0.5*|e|^2)
    float* slots   = e_sq + KK;                            // 256
    unsigned long long* packed_all = (unsigned long long*)(slots + 256);  // 512*136
    u16* rest_bf = (u16*)(packed_all + (size_t)BB * 136);  // 8192*256 bf16
    u16* emb_bf  = rest_bf + (size_t)BB * NN * CC;         // K*C bf16 (negated)

    float* f_hat = out;  // accumulate output in place

    hipMemsetAsync(out, 0, (size_t)BNC * sizeof(float), stream);
    hipMemcpyAsync(f_rest, f, (size_t)BNC * sizeof(float), hipMemcpyDeviceToDevice, stream);
    hipMemsetAsync(slots, 0, 256 * sizeof(float), stream);
    hipMemsetAsync(packed_all, 0xFF, (size_t)BB * 136 * sizeof(unsigned long long), stream);
    esq_kernel<<<KK / 4, 256, 0, stream>>>(emb, e_sq);
    cvt_emb_kernel<<<KK * CC / 4 / 256, 256, 0, stream>>>(emb, emb_bf);
    init_pool_kernel<<<BB, 256, 0, stream>>>(f, rest_bf);

    // splits: 128-row blocks -> grid = (4*pn) x splits; keep cpb >= 64
    static const int splits_tab[17] =
        {0,128,128,128,64,64,64,64,32,32,32,32,32,32,32,32,16};

    for (int pn = 1; pn <= NN; ++pn) {
        unsigned long long* packed = packed_all + (size_t)BB * (pn * (pn - 1) / 2);
        int splits = splits_tab[pn];
        int cpb = KK / splits;
        dim3 grid(BB * pn / 128, splits);
        dist_mfma_kernel<<<grid, 256, 0, stream>>>(rest_bf, emb_bf, e_sq, packed, cpb);
        update_pool_kernel<<<BB, 256, 0, stream>>>(f, emb, packed, f_rest, f_hat,
                                                   slots, rest_bf, pn);
    }
    final_kernel<<<1, 256, 0, stream>>>(slots, out + BNC);
}